// Round 1
// baseline (21.577 us; speedup 1.0000x reference)
//
#include <hip/hip_runtime.h>
#include <math.h>

#define TPB 256

// Rotated-box IoU via Sutherland–Hodgman clipping (convex quad ∩ convex quad).
// One thread per box pair. Polygon buffers live in LDS with transposed
// [slot][tid] layout so runtime slot indices never hit scratch and bank =
// tid%32 is conflict-free independent of per-lane divergence.
__global__ __launch_bounds__(TPB, 1) void diff_iou_rotated_kernel(
    const float* __restrict__ box1, const float* __restrict__ box2,
    float* __restrict__ out, int n)
{
    const int t = threadIdx.x;
    const int g = blockIdx.x * TPB + t;
    if (g >= n) return;

    // 2 ping-pong polygon buffers, 8 verts x (x,y) each = 16 float slots each.
    __shared__ float poly[32][TPB];

    const float* p1 = box1 + (size_t)g * 5;
    const float* p2 = box2 + (size_t)g * 5;
    const float x1 = p1[0], y1 = p1[1], w1 = p1[2], h1 = p1[3], a1 = p1[4];
    const float x2 = p2[0], y2 = p2[1], w2 = p2[2], h2 = p2[3], a2 = p2[4];

    float s1, c1; sincosf(a1, &s1, &c1);
    float s2, c2; sincosf(a2, &s2, &c2);

    // Corner offsets (CCW): (+,+), (-,+), (-,-), (+,-) scaled by w/2, h/2.
    const float sx[4] = {0.5f, -0.5f, -0.5f, 0.5f};
    const float sy[4] = {0.5f, 0.5f, -0.5f, -0.5f};

    // Clip polygon = corners of box1 (registers -> LDS buffer 0).
    #pragma unroll
    for (int i = 0; i < 4; ++i) {
        const float xx = sx[i] * w1, yy = sy[i] * h1;
        poly[2 * i][t]     = xx * c1 - yy * s1 + x1;
        poly[2 * i + 1][t] = xx * s1 + yy * c1 + y1;
    }
    // Clipper = corners of box2 (stay in registers, static indexing only).
    float c2x[4], c2y[4];
    #pragma unroll
    for (int i = 0; i < 4; ++i) {
        const float xx = sx[i] * w2, yy = sy[i] * h2;
        c2x[i] = xx * c2 - yy * s2 + x2;
        c2y[i] = xx * s2 + yy * c2 + y2;
    }

    int ncur = 4;
    int curB = 0, outB = 16;
    #pragma unroll 1
    for (int k = 0; k < 4; ++k) {
        if (ncur == 0) break;
        const float ax = c2x[k], ay = c2y[k];
        const float bx = c2x[(k + 1) & 3], by = c2y[(k + 1) & 3];
        const float ex = bx - ax, ey = by - ay;

        float Px = poly[curB][t], Py = poly[curB + 1][t];
        float dP = ex * (Py - ay) - ey * (Px - ax);
        const float P0x = Px, P0y = Py, d0 = dP;
        int m = 0;
        #pragma unroll 1
        for (int i = 0; i < ncur; ++i) {
            float Qx, Qy, dQ;
            if (i + 1 < ncur) {
                Qx = poly[curB + 2 * (i + 1)][t];
                Qy = poly[curB + 2 * (i + 1) + 1][t];
                dQ = ex * (Qy - ay) - ey * (Qx - ax);
            } else {
                Qx = P0x; Qy = P0y; dQ = d0;
            }
            const bool inP = (dP >= 0.0f);
            const bool inQ = (dQ >= 0.0f);
            if (inP) {
                poly[outB + 2 * m][t]     = Px;
                poly[outB + 2 * m + 1][t] = Py;
                ++m;
            }
            if (inP != inQ) {
                const float tt = dP / (dP - dQ);   // signs differ -> denom != 0
                poly[outB + 2 * m][t]     = Px + tt * (Qx - Px);
                poly[outB + 2 * m + 1][t] = Py + tt * (Qy - Py);
                ++m;
            }
            Px = Qx; Py = Qy; dP = dQ;
        }
        ncur = m;
        const int tmp = curB; curB = outB; outB = tmp;
    }

    // Triangle-fan shoelace (better conditioned than raw shoelace; equals it
    // exactly in exact arithmetic).
    float inter = 0.0f;
    if (ncur >= 3) {
        const float x0 = poly[curB][t], y0 = poly[curB + 1][t];
        float px = poly[curB + 2][t] - x0, py = poly[curB + 3][t] - y0;
        float acc = 0.0f;
        #pragma unroll 1
        for (int i = 2; i < ncur; ++i) {
            const float qx = poly[curB + 2 * i][t] - x0;
            const float qy = poly[curB + 2 * i + 1][t] - y0;
            acc += px * qy - py * qx;
            px = qx; py = qy;
        }
        inter = fabsf(acc) * 0.5f;
    }

    const float area1 = w1 * h1, area2 = w2 * h2;
    out[g] = inter / (area1 + area2 - inter);
}

extern "C" void kernel_launch(void* const* d_in, const int* in_sizes, int n_in,
                              void* d_out, int out_size, void* d_ws, size_t ws_size,
                              hipStream_t stream) {
    const float* b1 = (const float*)d_in[0];
    const float* b2 = (const float*)d_in[1];
    float* out = (float*)d_out;
    const int n = in_sizes[0] / 5;   // (B,N,5) -> B*N pairs
    const int blocks = (n + TPB - 1) / TPB;
    hipLaunchKernelGGL(diff_iou_rotated_kernel, dim3(blocks), dim3(TPB), 0, stream,
                       b1, b2, out, n);
}

// Round 2
// 13.975 us; speedup vs baseline: 1.5440x; 1.5440x over previous
//
#include <hip/hip_runtime.h>
#include <math.h>

#define TPB 256

#if __has_builtin(__builtin_amdgcn_rcpf)
__device__ __forceinline__ float frcp(float x) { return __builtin_amdgcn_rcpf(x); }
#else
__device__ __forceinline__ float frcp(float x) { return 1.0f / x; }
#endif

__device__ __forceinline__ float fclamp(float x, float lo, float hi) {
    return fminf(fmaxf(x, lo), hi);   // -> v_med3_f32
}

// Rotated-box IoU, branch-free, registers-only.
//
// Work in box1's local frame: box1 becomes the axis-aligned slab
// |x| <= W, |y| <= H. Clip box2's quad against the x-slab, then the y-slab
// with the shoelace fused in. Each edge emits EXACTLY 3 points:
//   e1 = P with the clipped coordinate clamped to the slab (projection onto
//        the nearest boundary line when outside; P itself when inside),
//   eA,eB = the slab-line crossings in traversal order (t = min/max of the
//        two line hits), each replaced by the previous emission when invalid.
// All degenerate emissions lie ON a boundary line; consecutive collinear
// points contribute zero net shoelace area (the cross-product sum
// telescopes), so the fixed 3-per-edge sequence has exactly the area of the
// true clipped polygon. Everything is compile-time indexed -> stays in VGPRs.
__global__ __launch_bounds__(TPB) void diff_iou_rotated_kernel(
    const float* __restrict__ box1, const float* __restrict__ box2,
    float* __restrict__ out, int n)
{
    const int g = blockIdx.x * TPB + threadIdx.x;
    if (g >= n) return;

    const float* p1 = box1 + (size_t)g * 5;
    const float* p2 = box2 + (size_t)g * 5;
    const float cx1 = p1[0], cy1 = p1[1], w1 = p1[2], h1 = p1[3], a1 = p1[4];
    const float cx2 = p2[0], cy2 = p2[1], w2 = p2[2], h2 = p2[3], a2 = p2[4];

    float s1, c1; sincosf(a1, &s1, &c1);
    float s2, c2; sincosf(a2, &s2, &c2);

    const float W = 0.5f * w1, H = 0.5f * h1;

    // box2 center in box1 frame (rotate by -a1), relative rotation a2-a1.
    const float dxc = cx2 - cx1, dyc = cy2 - cy1;
    const float lx =  c1 * dxc + s1 * dyc;
    const float ly = -s1 * dxc + c1 * dyc;
    const float cr = c2 * c1 + s2 * s1;   // cos(a2-a1)
    const float sr = s2 * c1 - c2 * s1;   // sin(a2-a1)

    // box2 corners in box1 frame (CCW).
    const float sx[4] = {0.5f, -0.5f, -0.5f, 0.5f};
    const float sy[4] = {0.5f, 0.5f, -0.5f, -0.5f};
    float vx[4], vy[4];
    #pragma unroll
    for (int i = 0; i < 4; ++i) {
        const float ox = sx[i] * w2, oy = sy[i] * h2;
        vx[i] = ox * cr - oy * sr + lx;
        vy[i] = ox * sr + oy * cr + ly;
    }

    // ---- Stage 1: clip against |x| <= W.  4 edges -> 12 emissions. ----
    float ux[12], uy[12];
    #pragma unroll
    for (int i = 0; i < 4; ++i) {
        const float px = vx[i],        py = vy[i];
        const float qx = vx[(i + 1) & 3], qy = vy[(i + 1) & 3];
        const float dx = qx - px, dy = qy - py;
        const float r  = frcp(dx);
        const float tl = (-W - px) * r;
        const float th = ( W - px) * r;
        const float tA = fminf(tl, th);
        const float tB = fmaxf(tl, th);
        const bool  vA = (tA > 0.0f) && (tA < 1.0f);
        const bool  vB = (tB > 0.0f) && (tB < 1.0f);

        const float e1x = fclamp(px, -W, W);
        const float e1y = py;
        const float xA = fclamp(px + tA * dx, -W, W);
        const float yA = py + tA * dy;
        const float eAx = vA ? xA : e1x;
        const float eAy = vA ? yA : e1y;
        const float xB = fclamp(px + tB * dx, -W, W);
        const float yB = py + tB * dy;
        const float eBx = vB ? xB : eAx;
        const float eBy = vB ? yB : eAy;

        ux[3 * i]     = e1x; uy[3 * i]     = e1y;
        ux[3 * i + 1] = eAx; uy[3 * i + 1] = eAy;
        ux[3 * i + 2] = eBx; uy[3 * i + 2] = eBy;
    }

    // ---- Stage 2: clip against |y| <= H, shoelace fused. ----
    float acc = 0.0f;
    float firstx = 0.0f, firsty = 0.0f, prevx = 0.0f, prevy = 0.0f;
    #pragma unroll
    for (int i = 0; i < 12; ++i) {
        const int j = (i + 1 == 12) ? 0 : i + 1;
        const float px = ux[i], py = uy[i];
        const float qx = ux[j], qy = uy[j];
        const float dx = qx - px, dy = qy - py;
        const float r  = frcp(dy);
        const float tl = (-H - py) * r;
        const float th = ( H - py) * r;
        const float tA = fminf(tl, th);
        const float tB = fmaxf(tl, th);
        const bool  vA = (tA > 0.0f) && (tA < 1.0f);
        const bool  vB = (tB > 0.0f) && (tB < 1.0f);

        const float e1x = px;
        const float e1y = fclamp(py, -H, H);
        const float yA = fclamp(py + tA * dy, -H, H);
        const float xA = px + tA * dx;
        const float eAx = vA ? xA : e1x;
        const float eAy = vA ? yA : e1y;
        const float yB = fclamp(py + tB * dy, -H, H);
        const float xB = px + tB * dx;
        const float eBx = vB ? xB : eAx;
        const float eBy = vB ? yB : eAy;

        if (i == 0) { firstx = e1x; firsty = e1y; }
        else        { acc += prevx * e1y - prevy * e1x; }
        acc += e1x * eAy - e1y * eAx;
        acc += eAx * eBy - eAy * eBx;
        prevx = eBx; prevy = eBy;
    }
    acc += prevx * firsty - prevy * firstx;

    const float inter = 0.5f * fabsf(acc);
    const float area1 = w1 * h1, area2 = w2 * h2;
    out[g] = inter / (area1 + area2 - inter);
}

extern "C" void kernel_launch(void* const* d_in, const int* in_sizes, int n_in,
                              void* d_out, int out_size, void* d_ws, size_t ws_size,
                              hipStream_t stream) {
    const float* b1 = (const float*)d_in[0];
    const float* b2 = (const float*)d_in[1];
    float* out = (float*)d_out;
    const int n = in_sizes[0] / 5;   // (B,N,5) -> B*N pairs
    const int blocks = (n + TPB - 1) / TPB;
    hipLaunchKernelGGL(diff_iou_rotated_kernel, dim3(blocks), dim3(TPB), 0, stream,
                       b1, b2, out, n);
}